// Round 3
// baseline (156.141 us; speedup 1.0000x reference)
//
#include <hip/hip_runtime.h>

#define DIM_IN   8192
#define DIM_OUT  8192
#define FAN      16
#define BATCH    1024
#define NNZ      (DIM_IN * FAN)
#define ROWS     4
#define BLOCK    1024
#define LDS_BYTES (DIM_IN * ROWS * 4)   // 128 KiB
#define ROUT     32                      // outputs owned per build block

// ---------------- build: range-scan, LDS atomics only ----------------------
// Block b owns outputs [b*ROUT, (b+1)*ROUT). Scans the whole edge list
// (coalesced, 4x unrolled for MLP), claims in-range edges via LDS atomicAdd,
// stores pre[] into per-output slots in LDS, then writes 32x16 ints coalesced.
// No global atomics; post (512KB) is L2-resident so the 256x redundant scan
// costs ~4-8us of L2 bandwidth total.
__global__ __launch_bounds__(1024)
void build_scan_kernel(const int* __restrict__ pre,
                       const int* __restrict__ post,
                       int* __restrict__ idx) {
    __shared__ int cnt[ROUT];
    __shared__ int sidx[ROUT * FAN];
    const int t  = threadIdx.x;
    const int j0 = blockIdx.x * ROUT;

    if (t < ROUT) cnt[t] = 0;
    __syncthreads();

    for (int base = 0; base < NNZ; base += 4096) {
        const int e0 = base + t;
        // 4 outstanding coalesced loads
        const int p0 = post[e0];
        const int p1 = post[e0 + 1024];
        const int p2 = post[e0 + 2048];
        const int p3 = post[e0 + 3072];

        const unsigned r0 = (unsigned)(p0 - j0);
        const unsigned r1 = (unsigned)(p1 - j0);
        const unsigned r2 = (unsigned)(p2 - j0);
        const unsigned r3 = (unsigned)(p3 - j0);

        if (r0 < ROUT) {
            int s = atomicAdd(&cnt[r0], 1);
            if (s < FAN) sidx[r0 * FAN + s] = pre[e0];
        }
        if (r1 < ROUT) {
            int s = atomicAdd(&cnt[r1], 1);
            if (s < FAN) sidx[r1 * FAN + s] = pre[e0 + 1024];
        }
        if (r2 < ROUT) {
            int s = atomicAdd(&cnt[r2], 1);
            if (s < FAN) sidx[r2 * FAN + s] = pre[e0 + 2048];
        }
        if (r3 < ROUT) {
            int s = atomicAdd(&cnt[r3], 1);
            if (s < FAN) sidx[r3 * FAN + s] = pre[e0 + 3072];
        }
    }
    __syncthreads();

    if (t < ROUT * FAN) idx[(size_t)j0 * FAN + t] = sidx[t];
}

// ---------------- main gather kernel ---------------------------------------
// 4 batch rows staged interleaved in LDS: lds[i*4 + r] = x[b0+r][i].
// Per output: 16 ds_read_b128 gathers (4 rows each), scale by 100, store.
__global__ __launch_bounds__(BLOCK, 4)
void gather_kernel(const float* __restrict__ x,
                   const int*   __restrict__ idx,
                   float*       __restrict__ y) {
    extern __shared__ float lds[];
    const int t  = threadIdx.x;
    const int b0 = blockIdx.x * ROWS;

    const float* xr0 = x + (size_t)(b0 + 0) * DIM_IN;
    const float* xr1 = x + (size_t)(b0 + 1) * DIM_IN;
    const float* xr2 = x + (size_t)(b0 + 2) * DIM_IN;
    const float* xr3 = x + (size_t)(b0 + 3) * DIM_IN;
#pragma unroll
    for (int c = 0; c < DIM_IN / BLOCK; ++c) {
        int i = t + c * BLOCK;
        float4 v;
        v.x = xr0[i];
        v.y = xr1[i];
        v.z = xr2[i];
        v.w = xr3[i];
        *reinterpret_cast<float4*>(&lds[i * 4]) = v;
    }
    __syncthreads();

    float* y0 = y + (size_t)(b0 + 0) * DIM_OUT;
    float* y1 = y + (size_t)(b0 + 1) * DIM_OUT;
    float* y2 = y + (size_t)(b0 + 2) * DIM_OUT;
    float* y3 = y + (size_t)(b0 + 3) * DIM_OUT;

#pragma unroll
    for (int o = 0; o < DIM_OUT / BLOCK; ++o) {
        const int j = t + o * BLOCK;
        const int4* ip = reinterpret_cast<const int4*>(idx + (size_t)j * FAN);
        int4 i0 = ip[0];
        int4 i1 = ip[1];
        int4 i2 = ip[2];
        int4 i3 = ip[3];

        float4 acc = make_float4(0.f, 0.f, 0.f, 0.f);
        auto accum = [&](int i) {
            float4 v = *reinterpret_cast<const float4*>(&lds[i * 4]);
            acc.x += v.x; acc.y += v.y; acc.z += v.z; acc.w += v.w;
        };
        accum(i0.x); accum(i0.y); accum(i0.z); accum(i0.w);
        accum(i1.x); accum(i1.y); accum(i1.z); accum(i1.w);
        accum(i2.x); accum(i2.y); accum(i2.z); accum(i2.w);
        accum(i3.x); accum(i3.y); accum(i3.z); accum(i3.w);

        y0[j] = 100.0f * acc.x;
        y1[j] = 100.0f * acc.y;
        y2[j] = 100.0f * acc.z;
        y3[j] = 100.0f * acc.w;
    }
}

// ---------------- launch ---------------------------------------------------
extern "C" void kernel_launch(void* const* d_in, const int* in_sizes, int n_in,
                              void* d_out, int out_size, void* d_ws, size_t ws_size,
                              hipStream_t stream) {
    const float* x    = (const float*)d_in[0];
    const int*   pre  = (const int*)d_in[1];
    const int*   post = (const int*)d_in[2];
    float*       y    = (float*)d_out;
    int*         idx  = (int*)d_ws;          // NNZ ints

    hipFuncSetAttribute((const void*)gather_kernel,
                        hipFuncAttributeMaxDynamicSharedMemorySize, LDS_BYTES);

    build_scan_kernel<<<DIM_OUT / ROUT, 1024, 0, stream>>>(pre, post, idx);
    gather_kernel<<<BATCH / ROWS, BLOCK, LDS_BYTES, stream>>>(x, idx, y);
}

// Round 4
// 120.530 us; speedup vs baseline: 1.2955x; 1.2955x over previous
//
#include <hip/hip_runtime.h>
#include <hip/hip_fp16.h>

#define DIM_IN   8192
#define DIM_OUT  8192
#define FAN      16
#define BATCH    1024
#define NNZ      (DIM_IN * FAN)
#define ROWS     8                       // batch rows per block (fp16 in LDS)
#define BLOCK    1024
#define OSPLIT   2                       // output-range split (keeps 256 blocks)
#define OCHUNK   (DIM_OUT / OSPLIT)      // 4096 outputs per block
#define LDS_BYTES (DIM_IN * ROWS * 2)    // 128 KiB
#define ROUT     32                      // outputs owned per build block

// ---------------- build: range-scan, LDS atomics only ----------------------
// Block b owns outputs [b*ROUT,(b+1)*ROUT). Scans the edge list (coalesced,
// 4x unrolled), claims in-range edges via LDS atomicAdd, writes 32x16 ints
// coalesced. post (512KB) is L2/L3-resident; whole kernel ~5us.
__global__ __launch_bounds__(1024)
void build_scan_kernel(const int* __restrict__ pre,
                       const int* __restrict__ post,
                       int* __restrict__ idx) {
    __shared__ int cnt[ROUT];
    __shared__ int sidx[ROUT * FAN];
    const int t  = threadIdx.x;
    const int j0 = blockIdx.x * ROUT;

    if (t < ROUT) cnt[t] = 0;
    __syncthreads();

    for (int base = 0; base < NNZ; base += 4096) {
        const int e0 = base + t;
        const int p0 = post[e0];
        const int p1 = post[e0 + 1024];
        const int p2 = post[e0 + 2048];
        const int p3 = post[e0 + 3072];

        const unsigned r0 = (unsigned)(p0 - j0);
        const unsigned r1 = (unsigned)(p1 - j0);
        const unsigned r2 = (unsigned)(p2 - j0);
        const unsigned r3 = (unsigned)(p3 - j0);

        if (r0 < ROUT) { int s = atomicAdd(&cnt[r0], 1); if (s < FAN) sidx[r0 * FAN + s] = pre[e0]; }
        if (r1 < ROUT) { int s = atomicAdd(&cnt[r1], 1); if (s < FAN) sidx[r1 * FAN + s] = pre[e0 + 1024]; }
        if (r2 < ROUT) { int s = atomicAdd(&cnt[r2], 1); if (s < FAN) sidx[r2 * FAN + s] = pre[e0 + 2048]; }
        if (r3 < ROUT) { int s = atomicAdd(&cnt[r3], 1); if (s < FAN) sidx[r3 * FAN + s] = pre[e0 + 3072]; }
    }
    __syncthreads();

    if (t < ROUT * FAN) idx[(size_t)j0 * FAN + t] = sidx[t];
}

// ---------------- main gather kernel ---------------------------------------
// 8 batch rows staged as fp16, interleaved: ldsh[i*8 + r] = (half)x[b0+r][i].
// One ds_read_b128 per gather serves all 8 rows (half the reads of the fp32
// ROWS=4 version; identical bank-conflict structure). fp32 accumulation.
__global__ __launch_bounds__(BLOCK, 1)
void gather_kernel(const float* __restrict__ x,
                   const int*   __restrict__ idx,
                   float*       __restrict__ y) {
    extern __shared__ __half ldsh[];
    const int t  = threadIdx.x;
    const int b0 = (blockIdx.x >> 1) * ROWS;       // row-group (128 groups)
    const int j0 = (blockIdx.x & 1) * OCHUNK;      // output half

    // Stage: 8 coalesced row streams, cvt to fp16, one b128 LDS write per i.
#pragma unroll
    for (int c = 0; c < DIM_IN / BLOCK; ++c) {
        const int i = t + c * BLOCK;
        uint4 w;
        {
            __half2 h;
            h.x = __float2half(x[(size_t)(b0 + 0) * DIM_IN + i]);
            h.y = __float2half(x[(size_t)(b0 + 1) * DIM_IN + i]);
            w.x = *reinterpret_cast<unsigned*>(&h);
            h.x = __float2half(x[(size_t)(b0 + 2) * DIM_IN + i]);
            h.y = __float2half(x[(size_t)(b0 + 3) * DIM_IN + i]);
            w.y = *reinterpret_cast<unsigned*>(&h);
            h.x = __float2half(x[(size_t)(b0 + 4) * DIM_IN + i]);
            h.y = __float2half(x[(size_t)(b0 + 5) * DIM_IN + i]);
            w.z = *reinterpret_cast<unsigned*>(&h);
            h.x = __float2half(x[(size_t)(b0 + 6) * DIM_IN + i]);
            h.y = __float2half(x[(size_t)(b0 + 7) * DIM_IN + i]);
            w.w = *reinterpret_cast<unsigned*>(&h);
        }
        *reinterpret_cast<uint4*>(&ldsh[(size_t)i * ROWS]) = w;
    }
    __syncthreads();

#pragma unroll
    for (int o = 0; o < OCHUNK / BLOCK; ++o) {
        const int j = j0 + t + o * BLOCK;
        const int4* ip = reinterpret_cast<const int4*>(idx + (size_t)j * FAN);
        int4 i0 = ip[0];
        int4 i1 = ip[1];
        int4 i2 = ip[2];
        int4 i3 = ip[3];

        float acc0 = 0.f, acc1 = 0.f, acc2 = 0.f, acc3 = 0.f;
        float acc4 = 0.f, acc5 = 0.f, acc6 = 0.f, acc7 = 0.f;

        auto accum = [&](int i) {
            const uint4 u = *reinterpret_cast<const uint4*>(&ldsh[(size_t)i * ROWS]);
            float2 f;
            f = __half22float2(*reinterpret_cast<const __half2*>(&u.x));
            acc0 += f.x; acc1 += f.y;
            f = __half22float2(*reinterpret_cast<const __half2*>(&u.y));
            acc2 += f.x; acc3 += f.y;
            f = __half22float2(*reinterpret_cast<const __half2*>(&u.z));
            acc4 += f.x; acc5 += f.y;
            f = __half22float2(*reinterpret_cast<const __half2*>(&u.w));
            acc6 += f.x; acc7 += f.y;
        };
        accum(i0.x); accum(i0.y); accum(i0.z); accum(i0.w);
        accum(i1.x); accum(i1.y); accum(i1.z); accum(i1.w);
        accum(i2.x); accum(i2.y); accum(i2.z); accum(i2.w);
        accum(i3.x); accum(i3.y); accum(i3.z); accum(i3.w);

        y[(size_t)(b0 + 0) * DIM_OUT + j] = 100.0f * acc0;
        y[(size_t)(b0 + 1) * DIM_OUT + j] = 100.0f * acc1;
        y[(size_t)(b0 + 2) * DIM_OUT + j] = 100.0f * acc2;
        y[(size_t)(b0 + 3) * DIM_OUT + j] = 100.0f * acc3;
        y[(size_t)(b0 + 4) * DIM_OUT + j] = 100.0f * acc4;
        y[(size_t)(b0 + 5) * DIM_OUT + j] = 100.0f * acc5;
        y[(size_t)(b0 + 6) * DIM_OUT + j] = 100.0f * acc6;
        y[(size_t)(b0 + 7) * DIM_OUT + j] = 100.0f * acc7;
    }
}

// ---------------- launch ---------------------------------------------------
extern "C" void kernel_launch(void* const* d_in, const int* in_sizes, int n_in,
                              void* d_out, int out_size, void* d_ws, size_t ws_size,
                              hipStream_t stream) {
    const float* x    = (const float*)d_in[0];
    const int*   pre  = (const int*)d_in[1];
    const int*   post = (const int*)d_in[2];
    float*       y    = (float*)d_out;
    int*         idx  = (int*)d_ws;          // NNZ ints

    hipFuncSetAttribute((const void*)gather_kernel,
                        hipFuncAttributeMaxDynamicSharedMemorySize, LDS_BYTES);

    build_scan_kernel<<<DIM_OUT / ROUT, 1024, 0, stream>>>(pre, post, idx);
    gather_kernel<<<(BATCH / ROWS) * OSPLIT, BLOCK, LDS_BYTES, stream>>>(x, idx, y);
}